// Round 1
// baseline (214.964 us; speedup 1.0000x reference)
//
#include <hip/hip_runtime.h>
#include <math.h>

#define B_  32
#define T_  4096
#define D_  512
#define V_  32000
#define KW  128     // truncated window: 0.9^128 = 1.4e-6 -> output error bound ~3e-5 << 6.7e-3

// -----------------------------------------------------------------------------
// Kernel 1: h[b][e] = sum_{twin=0..KW-1} 0.1*0.9^(KW-1-twin)
//                         * tanh( dot(emb[x[b, T-KW+twin]], Ww[e,:]) + Wb[e] )
// Grid: 32 b * 8 e-chunks(64) = 256 blocks, 256 threads.
// Tile: 128 t x 64 e, per-thread 8t x 4e, d-tile 16, transposed LDS tiles so
// compute reads are ds_read_b128 along contiguous t / e.
// -----------------------------------------------------------------------------
__global__ __launch_bounds__(256) void k_hidden(const int* __restrict__ x,
                                                const float* __restrict__ emb,
                                                const float* __restrict__ Ww,
                                                const float* __restrict__ Wb,
                                                float* __restrict__ h) {
    __shared__ int rows[KW];
    __shared__ __align__(16) float Es[16][132];  // [dd][t], stride 132 (16B-aligned rows, odd-ish banks)
    __shared__ __align__(16) float Ws[16][68];   // [dd][e]
    __shared__ float red[16][65];                // t-group partial reduction

    const int tid = threadIdx.x;
    const int b  = blockIdx.x >> 3;
    const int e0 = (blockIdx.x & 7) * 64;

    if (tid < KW) rows[tid] = x[b * T_ + (T_ - KW) + tid];
    __syncthreads();

    const int tx = tid & 15;   // e-group: e_local = tx*4 + j
    const int ty = tid >> 4;   // t-group: t = ty*8 + i

    float acc[8][4];
#pragma unroll
    for (int i = 0; i < 8; i++)
#pragma unroll
        for (int j = 0; j < 4; j++) acc[i][j] = 0.f;

    // loader mappings
    const int lt  = tid >> 1;         // Es: row t, each thread loads 2 float4 (q=lq, lq+1)
    const int lq  = (tid & 1) * 2;
    const int le  = tid >> 2;         // Ws: row e, 1 float4 (q=lwq)
    const int lwq = tid & 3;

    for (int d0 = 0; d0 < D_; d0 += 16) {
        // stage E tile (gathered embedding rows), transposed into [dd][t]
#pragma unroll
        for (int r = 0; r < 2; r++) {
            const int q = lq + r;
            const float4 v = *(const float4*)&emb[(size_t)rows[lt] * D_ + d0 + q * 4];
            Es[q * 4 + 0][lt] = v.x;
            Es[q * 4 + 1][lt] = v.y;
            Es[q * 4 + 2][lt] = v.z;
            Es[q * 4 + 3][lt] = v.w;
        }
        // stage W tile, transposed into [dd][e]
        {
            const float4 v = *(const float4*)&Ww[(size_t)(e0 + le) * D_ + d0 + lwq * 4];
            Ws[lwq * 4 + 0][le] = v.x;
            Ws[lwq * 4 + 1][le] = v.y;
            Ws[lwq * 4 + 2][le] = v.z;
            Ws[lwq * 4 + 3][le] = v.w;
        }
        __syncthreads();

#pragma unroll
        for (int dd = 0; dd < 16; dd++) {
            const float4 a0 = *(const float4*)&Es[dd][ty * 8];
            const float4 a1 = *(const float4*)&Es[dd][ty * 8 + 4];
            const float4 wv = *(const float4*)&Ws[dd][tx * 4];
            const float a[8] = {a0.x, a0.y, a0.z, a0.w, a1.x, a1.y, a1.z, a1.w};
            const float w[4] = {wv.x, wv.y, wv.z, wv.w};
#pragma unroll
            for (int i = 0; i < 8; i++)
#pragma unroll
                for (int j = 0; j < 4; j++) acc[i][j] += a[i] * w[j];
        }
        __syncthreads();
    }

    // epilogue: tanh + geometric weight, reduce over the 16 t-groups
    float p[4] = {0.f, 0.f, 0.f, 0.f};
    const float wb0 = Wb[e0 + tx * 4 + 0];
    const float wb1 = Wb[e0 + tx * 4 + 1];
    const float wb2 = Wb[e0 + tx * 4 + 2];
    const float wb3 = Wb[e0 + tx * 4 + 3];
#pragma unroll
    for (int i = 0; i < 8; i++) {
        const int twin = ty * 8 + i;
        const float wt = 0.1f * powf(0.9f, (float)(KW - 1 - twin));
        p[0] += wt * tanhf(acc[i][0] + wb0);
        p[1] += wt * tanhf(acc[i][1] + wb1);
        p[2] += wt * tanhf(acc[i][2] + wb2);
        p[3] += wt * tanhf(acc[i][3] + wb3);
    }
#pragma unroll
    for (int j = 0; j < 4; j++) red[ty][tx * 4 + j] = p[j];
    __syncthreads();
    if (tid < 64) {
        float s = 0.f;
#pragma unroll
        for (int k = 0; k < 16; k++) s += red[k][tid];
        h[b * D_ + e0 + tid] = s;
    }
}

// -----------------------------------------------------------------------------
// Kernel 2: out[b][v] = dot(h[b,:], head_w[v,:]) + head_b[v]
// Grid: 250 blocks * 256 threads; v-tile 128 per block.
// h[32][512] staged in LDS (64 KB); whole wave shares one b-group -> every LDS
// read is a single-address broadcast. Per thread: 2 v-rows streamed from HBM
// (float4), 8 b accumulators each -> 1 global f4 drives 32 FMAs.
// -----------------------------------------------------------------------------
__global__ __launch_bounds__(256) void k_head(const float* __restrict__ h,
                                              const float* __restrict__ Whead,
                                              const float* __restrict__ bhead,
                                              float* __restrict__ out) {
    __shared__ __align__(16) float Hs[B_ * D_];  // 64 KB

    const int tid = threadIdx.x;
#pragma unroll
    for (int r = 0; r < 16; r++) {
        const int f = tid + 256 * r;
        *(float4*)&Hs[f * 4] = *(const float4*)&h[f * 4];
    }
    __syncthreads();

    const int vg = tid & 63;
    const int bg = tid >> 6;                 // 0..3 -> b = bg*8 + i (uniform per wave)
    const int v0 = blockIdx.x * 128;

    float acc[2][8];
#pragma unroll
    for (int k = 0; k < 2; k++)
#pragma unroll
        for (int i = 0; i < 8; i++) acc[k][i] = 0.f;

    const float* __restrict__ w0p = &Whead[(size_t)(v0 + vg) * D_];
    const float* __restrict__ w1p = &Whead[(size_t)(v0 + vg + 64) * D_];
    const float* __restrict__ hp  = &Hs[bg * 8 * D_];

    for (int d = 0; d < D_; d += 4) {
        const float4 w0 = *(const float4*)&w0p[d];
        const float4 w1 = *(const float4*)&w1p[d];
#pragma unroll
        for (int i = 0; i < 8; i++) {
            const float4 hv = *(const float4*)&hp[i * D_ + d];
            acc[0][i] += w0.x * hv.x + w0.y * hv.y + w0.z * hv.z + w0.w * hv.w;
            acc[1][i] += w1.x * hv.x + w1.y * hv.y + w1.z * hv.z + w1.w * hv.w;
        }
    }

    const float hb0 = bhead[v0 + vg];
    const float hb1 = bhead[v0 + vg + 64];
#pragma unroll
    for (int i = 0; i < 8; i++) {
        const int b = bg * 8 + i;
        out[(size_t)b * V_ + v0 + vg]      = acc[0][i] + hb0;
        out[(size_t)b * V_ + v0 + vg + 64] = acc[1][i] + hb1;
    }
}

extern "C" void kernel_launch(void* const* d_in, const int* in_sizes, int n_in,
                              void* d_out, int out_size, void* d_ws, size_t ws_size,
                              hipStream_t stream) {
    const int*   x      = (const int*)d_in[0];
    const float* emb    = (const float*)d_in[1];
    const float* W_w    = (const float*)d_in[2];
    const float* W_b    = (const float*)d_in[3];
    const float* head_w = (const float*)d_in[4];
    const float* head_b = (const float*)d_in[5];
    float* out = (float*)d_out;
    float* hbuf = (float*)d_ws;  // 32*512 floats = 64 KB, fully written by k_hidden

    k_hidden<<<dim3(B_ * (D_ / 64)), dim3(256), 0, stream>>>(x, emb, W_w, W_b, hbuf);
    k_head<<<dim3(V_ / 128), dim3(256), 0, stream>>>(hbuf, head_w, head_b, out);
}

// Round 2
// 180.741 us; speedup vs baseline: 1.1893x; 1.1893x over previous
//
#include <hip/hip_runtime.h>
#include <math.h>
#include <stdint.h>

#define B_  32
#define T_  4096
#define D_  512
#define V_  32000
#define KW  128   // 0.9^128 = 1.4e-6 -> truncation error ~3e-5 at output, << 6.7e-3

typedef __attribute__((ext_vector_type(8))) short bf16x8_t;   // MFMA A/B frag (4 VGPRs)
typedef __attribute__((ext_vector_type(4))) float f32x4_t;    // MFMA C/D frag

// fp32 -> bf16 round-to-nearest-even
__device__ inline unsigned short f2bf(float f) {
    union { float f; uint32_t u; } c; c.f = f;
    return (unsigned short)((c.u + 0x7FFFu + ((c.u >> 16) & 1u)) >> 16);
}

// -----------------------------------------------------------------------------
// k_cvtw: Ww fp32 [512][512] -> bf16, once. 128 blocks x 256 thr x 8 elems.
// -----------------------------------------------------------------------------
__global__ __launch_bounds__(256) void k_cvtw(const float* __restrict__ Ww,
                                              unsigned short* __restrict__ Wbf) {
    const int idx = (blockIdx.x * 256 + threadIdx.x) * 8;
    const float4 a = *(const float4*)&Ww[idx];
    const float4 b = *(const float4*)&Ww[idx + 4];
    union { unsigned short s[8]; uint4 v; } o;
    o.s[0] = f2bf(a.x); o.s[1] = f2bf(a.y); o.s[2] = f2bf(a.z); o.s[3] = f2bf(a.w);
    o.s[4] = f2bf(b.x); o.s[5] = f2bf(b.y); o.s[6] = f2bf(b.z); o.s[7] = f2bf(b.w);
    *(uint4*)&Wbf[idx] = o.v;
}

// -----------------------------------------------------------------------------
// k_hidden: h[b][e] = sum_twin 0.1*0.9^(127-twin) * tanh(dot(emb[x],Ww[e])+Wb[e])
// bf16 MFMA 16x16x32 GEMM, M=128 (one b's window) x N=64 per block, K=512.
// Grid 256 blocks (32 b x 8 e-chunks), 256 thr. Wave w: M-rows [32w,32w+32),
// full N=64 -> acc = 2 Mtiles x 4 Ntiles x f32x4. Weighted-t reduce fused in
// epilogue. A staged via gather+cvt (manual ds_write_b128), B via
// global_load_lds width=16 from pre-converted Wbf.
// -----------------------------------------------------------------------------
__global__ __launch_bounds__(256) void k_hidden(const int* __restrict__ x,
                                                const float* __restrict__ emb,
                                                const unsigned short* __restrict__ Wbf,
                                                const float* __restrict__ Wb,
                                                float* __restrict__ h) {
    __shared__ int rows[KW];
    __shared__ __align__(16) unsigned short As[KW * 32];  // [m][k] 128x32 bf16, 8 KB
    __shared__ __align__(16) unsigned short Bs[64 * 32];  // [n][k] 64x32 bf16, 4 KB
    __shared__ float red[16][64];                         // (wave,quad) partials, 4 KB

    const int tid = threadIdx.x;
    const int b   = blockIdx.x >> 3;
    const int e0  = (blockIdx.x & 7) * 64;

    if (tid < KW) rows[tid] = x[b * T_ + (T_ - KW) + tid];
    __syncthreads();

    const int lane = tid & 63;
    const int w    = tid >> 6;
    const int m15  = lane & 15;
    const int q    = lane >> 4;

    f32x4_t acc[2][4];
#pragma unroll
    for (int mi = 0; mi < 2; mi++)
#pragma unroll
        for (int ni = 0; ni < 4; ni++) acc[mi][ni] = (f32x4_t){0.f, 0.f, 0.f, 0.f};

    for (int k0 = 0; k0 < D_; k0 += 32) {
        __syncthreads();  // previous iter's frag reads done before overwrite
        // stage A: gather emb rows, cvt fp32->bf16, 16 B per ds_write
#pragma unroll
        for (int s = 0; s < 2; s++) {
            const int j  = tid + s * 256;     // 512 chunks of 8 elems
            const int r  = j >> 2;            // m row 0..127
            const int kc = j & 3;             // k sub-chunk
            const float* src = emb + (size_t)rows[r] * D_ + k0 + kc * 8;
            const float4 a0 = *(const float4*)src;
            const float4 a1 = *(const float4*)(src + 4);
            union { unsigned short s[8]; uint4 v; } o;
            o.s[0] = f2bf(a0.x); o.s[1] = f2bf(a0.y); o.s[2] = f2bf(a0.z); o.s[3] = f2bf(a0.w);
            o.s[4] = f2bf(a1.x); o.s[5] = f2bf(a1.y); o.s[6] = f2bf(a1.z); o.s[7] = f2bf(a1.w);
            *(uint4*)&As[j * 8] = o.v;
        }
        // stage B: async global->LDS, 16 B/lane, lane-contiguous layout
        {
            const unsigned short* src = Wbf + (size_t)(e0 + (tid >> 2)) * D_ + k0 + (tid & 3) * 8;
            __builtin_amdgcn_global_load_lds(
                (const __attribute__((address_space(1))) void*)src,
                (__attribute__((address_space(3))) void*)&Bs[tid * 8], 16, 0, 0);
        }
        __syncthreads();

        bf16x8_t af[2], bfr[4];
#pragma unroll
        for (int mi = 0; mi < 2; mi++)
            af[mi] = *(const bf16x8_t*)&As[(w * 32 + mi * 16 + m15) * 32 + q * 8];
#pragma unroll
        for (int ni = 0; ni < 4; ni++)
            bfr[ni] = *(const bf16x8_t*)&Bs[(ni * 16 + m15) * 32 + q * 8];
#pragma unroll
        for (int mi = 0; mi < 2; mi++)
#pragma unroll
            for (int ni = 0; ni < 4; ni++)
                acc[mi][ni] = __builtin_amdgcn_mfma_f32_16x16x32_bf16(
                    af[mi], bfr[ni], acc[mi][ni], 0, 0, 0);
    }

    // epilogue: tanh + geometric weight + in-block t-reduction
    // D layout (m89/m91-verified): row = q*4 + reg (M), col = m15 (N)
    float p[4] = {0.f, 0.f, 0.f, 0.f};
#pragma unroll
    for (int ni = 0; ni < 4; ni++) {
        const float wbv = Wb[e0 + ni * 16 + m15];
#pragma unroll
        for (int mi = 0; mi < 2; mi++)
#pragma unroll
            for (int r = 0; r < 4; r++) {
                const int twin = w * 32 + mi * 16 + q * 4 + r;
                const float pre = acc[mi][ni][r] + wbv;
                const float e2 = __expf(2.f * pre);
                const float u  = (e2 - 1.f) / (e2 + 1.f);           // tanh
                const float wt = 0.1f * exp2f((float)(127 - twin) * -0.15200309344504995f);
                p[ni] += wt * u;
            }
    }
#pragma unroll
    for (int ni = 0; ni < 4; ni++) red[w * 4 + q][ni * 16 + m15] = p[ni];
    __syncthreads();
    if (tid < 64) {
        float s = 0.f;
#pragma unroll
        for (int g = 0; g < 16; g++) s += red[g][tid];
        h[b * D_ + e0 + tid] = s;
    }
}

// -----------------------------------------------------------------------------
// k_head: out[b][v] = dot(h[b], head_w[v]) + head_b[v]
// 500 blocks x 256 thr (2 blocks/CU, 8 waves/CU). Wave = 64 v-rows x 8 b's.
// h read via wave-uniform pointer -> scalar (s_load) broadcasts: zero LDS in
// the loop. head_w rows streamed once (float4). HBM-bound target ~11 us.
// -----------------------------------------------------------------------------
__global__ __launch_bounds__(256) void k_head(const float* __restrict__ h,
                                              const float* __restrict__ Whead,
                                              const float* __restrict__ bhead,
                                              float* __restrict__ out) {
    const int lane = threadIdx.x & 63;
    const int wv   = threadIdx.x >> 6;
    const int bg   = __builtin_amdgcn_readfirstlane(wv) * 8;  // uniform b-group
    const int v    = blockIdx.x * 64 + lane;

    const float* __restrict__ wp = Whead + (size_t)v * D_;
    const float* __restrict__ hp = h + bg * D_;               // uniform pointer

    float acc[8];
#pragma unroll
    for (int i = 0; i < 8; i++) acc[i] = 0.f;

#pragma unroll 4
    for (int d = 0; d < D_; d += 4) {
        const float4 wv4 = *(const float4*)&wp[d];
#pragma unroll
        for (int i = 0; i < 8; i++) {
            const float4 hv = *(const float4*)&hp[i * D_ + d];  // s_load_dwordx4
            acc[i] += wv4.x * hv.x + wv4.y * hv.y + wv4.z * hv.z + wv4.w * hv.w;
        }
    }

    const float bb = bhead[v];
#pragma unroll
    for (int i = 0; i < 8; i++)
        out[(size_t)(bg + i) * V_ + v] = acc[i] + bb;
}

extern "C" void kernel_launch(void* const* d_in, const int* in_sizes, int n_in,
                              void* d_out, int out_size, void* d_ws, size_t ws_size,
                              hipStream_t stream) {
    const int*   x      = (const int*)d_in[0];
    const float* emb    = (const float*)d_in[1];
    const float* W_w    = (const float*)d_in[2];
    const float* W_b    = (const float*)d_in[3];
    const float* head_w = (const float*)d_in[4];
    const float* head_b = (const float*)d_in[5];
    float* out = (float*)d_out;

    unsigned short* Wbf = (unsigned short*)d_ws;                    // 512 KB
    float* hbuf = (float*)((char*)d_ws + 512 * 1024);               // 64 KB

    k_cvtw  <<<dim3(128),      dim3(256), 0, stream>>>(W_w, Wbf);
    k_hidden<<<dim3(256),      dim3(256), 0, stream>>>(x, emb, Wbf, W_b, hbuf);
    k_head  <<<dim3(V_ / 64),  dim3(256), 0, stream>>>(hbuf, head_w, head_b, out);
}

// Round 3
// 169.264 us; speedup vs baseline: 1.2700x; 1.0678x over previous
//
#include <hip/hip_runtime.h>
#include <math.h>
#include <stdint.h>

#define B_  32
#define T_  4096
#define D_  512
#define V_  32000
#define KW  128   // 0.9^128 = 1.4e-6 -> truncation error ~2e-5 at output, << 6.7e-3

typedef __attribute__((ext_vector_type(8))) short bf16x8_t;   // MFMA A/B frag (4 VGPRs)
typedef __attribute__((ext_vector_type(4))) float f32x4_t;    // MFMA C/D frag

// fp32 -> bf16 round-to-nearest-even
__device__ inline unsigned short f2bf(float f) {
    union { float f; uint32_t u; } c; c.f = f;
    return (unsigned short)((c.u + 0x7FFFu + ((c.u >> 16) & 1u)) >> 16);
}
__device__ inline float bf2f(unsigned short s) {
    union { uint32_t u; float f; } c; c.u = ((uint32_t)s) << 16;
    return c.f;
}

// -----------------------------------------------------------------------------
// k_cvtw: Ww fp32 [512][512] -> bf16 (once per launch) + zero hbuf for the
// atomic partial-sum accumulation in k_hidden. 128 blocks x 256 thr.
// -----------------------------------------------------------------------------
__global__ __launch_bounds__(256) void k_cvtw(const float* __restrict__ Ww,
                                              unsigned short* __restrict__ Wbf,
                                              float* __restrict__ hbuf) {
    const int gid = blockIdx.x * 256 + threadIdx.x;   // 0..32767
    const int idx = gid * 8;
    const float4 a = *(const float4*)&Ww[idx];
    const float4 b = *(const float4*)&Ww[idx + 4];
    union { unsigned short s[8]; uint4 v; } o;
    o.s[0] = f2bf(a.x); o.s[1] = f2bf(a.y); o.s[2] = f2bf(a.z); o.s[3] = f2bf(a.w);
    o.s[4] = f2bf(b.x); o.s[5] = f2bf(b.y); o.s[6] = f2bf(b.z); o.s[7] = f2bf(b.w);
    *(uint4*)&Wbf[idx] = o.v;
    if (gid < B_ * D_) hbuf[gid] = 0.f;
}

// -----------------------------------------------------------------------------
// k_hidden: partial h[b][e] over a 32-row window slice.
// Grid 1024 = 32 b x 8 e-chunks(64) x 4 t-slices(32) -> 4 blocks/CU.
// Per block: bf16 MFMA GEMM M=32 x N=64, K=512 (16 k-steps of 32).
// Wave w: M-tile = w&1, N-half(32) = w>>1 -> 2 MFMAs/wave/k-step.
// Epilogue: tanh + geometric weight + in-block reduce + atomicAdd to hbuf.
// -----------------------------------------------------------------------------
__global__ __launch_bounds__(256) void k_hidden(const int* __restrict__ x,
                                                const float* __restrict__ emb,
                                                const unsigned short* __restrict__ Wbf,
                                                const float* __restrict__ Wb,
                                                float* __restrict__ h) {
    __shared__ int rows[32];
    __shared__ __align__(16) unsigned short As[32 * 32];  // [m][k] 2 KB
    __shared__ __align__(16) unsigned short Bs[64 * 32];  // [n][k] 4 KB
    __shared__ float red[8][64];                          // 2 KB

    const int tid = threadIdx.x;
    const int b   = blockIdx.x >> 5;
    const int e0  = ((blockIdx.x >> 2) & 7) * 64;
    const int tb  = blockIdx.x & 3;

    if (tid < 32) rows[tid] = x[b * T_ + (T_ - KW) + tb * 32 + tid];
    __syncthreads();

    const int lane = tid & 63;
    const int w    = tid >> 6;
    const int m15  = lane & 15;
    const int q    = lane >> 4;
    const int mt   = w & 1;    // M-tile (16 rows)
    const int nh   = w >> 1;   // N-half (32 cols)

    f32x4_t acc[2];
    acc[0] = (f32x4_t){0.f, 0.f, 0.f, 0.f};
    acc[1] = (f32x4_t){0.f, 0.f, 0.f, 0.f};

    for (int k0 = 0; k0 < D_; k0 += 32) {
        __syncthreads();  // frag reads of previous iter done before overwrite
        // stage A: gather 32 emb rows, fp32->bf16, threads 0..127
        if (tid < 128) {
            const float* src = emb + (size_t)rows[tid >> 2] * D_ + k0 + (tid & 3) * 8;
            const float4 a0 = *(const float4*)src;
            const float4 a1 = *(const float4*)(src + 4);
            union { unsigned short s[8]; uint4 v; } o;
            o.s[0] = f2bf(a0.x); o.s[1] = f2bf(a0.y); o.s[2] = f2bf(a0.z); o.s[3] = f2bf(a0.w);
            o.s[4] = f2bf(a1.x); o.s[5] = f2bf(a1.y); o.s[6] = f2bf(a1.z); o.s[7] = f2bf(a1.w);
            *(uint4*)&As[tid * 8] = o.v;
        }
        // stage B: async global->LDS 16 B/lane, lane-contiguous (wave-uniform+lane*16)
        {
            const unsigned short* src = Wbf + (size_t)(e0 + (tid >> 2)) * D_ + k0 + (tid & 3) * 8;
            __builtin_amdgcn_global_load_lds(
                (const __attribute__((address_space(1))) void*)src,
                (__attribute__((address_space(3))) void*)&Bs[tid * 8], 16, 0, 0);
        }
        __syncthreads();

        const bf16x8_t af  = *(const bf16x8_t*)&As[(mt * 16 + m15) * 32 + q * 8];
        const bf16x8_t bf0 = *(const bf16x8_t*)&Bs[(nh * 32 + m15) * 32 + q * 8];
        const bf16x8_t bf1 = *(const bf16x8_t*)&Bs[(nh * 32 + 16 + m15) * 32 + q * 8];
        acc[0] = __builtin_amdgcn_mfma_f32_16x16x32_bf16(af, bf0, acc[0], 0, 0, 0);
        acc[1] = __builtin_amdgcn_mfma_f32_16x16x32_bf16(af, bf1, acc[1], 0, 0, 0);
    }

    // epilogue: tanh + geometric weight; C/D: row(M)=q*4+r, col(N)=m15
    float p[2] = {0.f, 0.f};
#pragma unroll
    for (int ni = 0; ni < 2; ni++) {
        const float wbv = Wb[e0 + nh * 32 + ni * 16 + m15];
#pragma unroll
        for (int r = 0; r < 4; r++) {
            const int twin = tb * 32 + mt * 16 + q * 4 + r;
            const float pre = acc[ni][r] + wbv;
            const float e2  = __expf(2.f * pre);
            const float u   = (e2 - 1.f) / (e2 + 1.f);
            const float wt  = 0.1f * exp2f((float)(127 - twin) * -0.15200309344504995f);
            p[ni] += wt * u;
        }
    }
#pragma unroll
    for (int ni = 0; ni < 2; ni++)
        red[mt * 4 + q][nh * 32 + ni * 16 + m15] = p[ni];
    __syncthreads();
    if (tid < 64) {
        float s = 0.f;
#pragma unroll
        for (int g = 0; g < 8; g++) s += red[g][tid];
        atomicAdd(&h[b * D_ + e0 + tid], s);
    }
}

// -----------------------------------------------------------------------------
// k_hsplit: h fp32 -> (h_hi, h_lo) bf16 split (exact to ~2^-17 rel).
// -----------------------------------------------------------------------------
__global__ __launch_bounds__(256) void k_hsplit(const float* __restrict__ h,
                                                unsigned short* __restrict__ hhi,
                                                unsigned short* __restrict__ hlo) {
    const int i = blockIdx.x * 256 + threadIdx.x;   // 16384 total
    const float v = h[i];
    const unsigned short hi = f2bf(v);
    hhi[i] = hi;
    hlo[i] = f2bf(v - bf2f(hi));
}

// -----------------------------------------------------------------------------
// k_head: out[32][32000] = h @ head_w^T + head_b via split-bf16 MFMA.
// 500 blocks x 256 thr (8 waves/CU). Wave = one 16-col v-tile, M=32 (2 tiles).
// B-frags loaded straight from fp32 head_w into registers (frag layout:
// n=lane&15, k-octet=lane>>4), converted to bf16 hi+lo in VGPRs. 3 MFMAs per
// (mt,kstep): Ahi*Bhi + Ahi*Blo + Alo*Bhi => fp32-accurate. Pure HBM stream.
// -----------------------------------------------------------------------------
__global__ __launch_bounds__(256) void k_head(const unsigned short* __restrict__ hhi,
                                              const unsigned short* __restrict__ hlo,
                                              const float* __restrict__ Whead,
                                              const float* __restrict__ bhead,
                                              float* __restrict__ out) {
    const int lane = threadIdx.x & 63;
    const int w    = threadIdx.x >> 6;
    const int n    = lane & 15;
    const int q    = lane >> 4;
    const int v    = blockIdx.x * 64 + w * 16 + n;

    f32x4_t acc[2];
    acc[0] = (f32x4_t){0.f, 0.f, 0.f, 0.f};
    acc[1] = (f32x4_t){0.f, 0.f, 0.f, 0.f};

    const float* __restrict__ wp = Whead + (size_t)v * D_ + q * 8;
    const unsigned short* __restrict__ ah0 = hhi + n * D_ + q * 8;
    const unsigned short* __restrict__ ah1 = hhi + (16 + n) * D_ + q * 8;
    const unsigned short* __restrict__ al0 = hlo + n * D_ + q * 8;
    const unsigned short* __restrict__ al1 = hlo + (16 + n) * D_ + q * 8;

#pragma unroll 2
    for (int ks = 0; ks < 16; ks++) {
        const int off = ks * 32;
        const float4 w0 = *(const float4*)&wp[off];
        const float4 w1 = *(const float4*)&wp[off + 4];
        const bf16x8_t a0h = *(const bf16x8_t*)&ah0[off];
        const bf16x8_t a1h = *(const bf16x8_t*)&ah1[off];
        const bf16x8_t a0l = *(const bf16x8_t*)&al0[off];
        const bf16x8_t a1l = *(const bf16x8_t*)&al1[off];

        const float wf[8] = {w0.x, w0.y, w0.z, w0.w, w1.x, w1.y, w1.z, w1.w};
        union { unsigned short s[8]; bf16x8_t v; } bh, bl;
#pragma unroll
        for (int j = 0; j < 8; j++) {
            const unsigned short hi = f2bf(wf[j]);
            bh.s[j] = hi;
            bl.s[j] = f2bf(wf[j] - bf2f(hi));
        }
        acc[0] = __builtin_amdgcn_mfma_f32_16x16x32_bf16(a0h, bh.v, acc[0], 0, 0, 0);
        acc[1] = __builtin_amdgcn_mfma_f32_16x16x32_bf16(a1h, bh.v, acc[1], 0, 0, 0);
        acc[0] = __builtin_amdgcn_mfma_f32_16x16x32_bf16(a0l, bh.v, acc[0], 0, 0, 0);
        acc[1] = __builtin_amdgcn_mfma_f32_16x16x32_bf16(a1l, bh.v, acc[1], 0, 0, 0);
        acc[0] = __builtin_amdgcn_mfma_f32_16x16x32_bf16(a0h, bl.v, acc[0], 0, 0, 0);
        acc[1] = __builtin_amdgcn_mfma_f32_16x16x32_bf16(a1h, bl.v, acc[1], 0, 0, 0);
    }

    // C/D: row(M: b) = mt*16 + q*4 + r, col(N: v) = n
    const float bb = bhead[v];
#pragma unroll
    for (int mtl = 0; mtl < 2; mtl++)
#pragma unroll
        for (int r = 0; r < 4; r++)
            out[(size_t)(mtl * 16 + q * 4 + r) * V_ + v] = acc[mtl][r] + bb;
}

extern "C" void kernel_launch(void* const* d_in, const int* in_sizes, int n_in,
                              void* d_out, int out_size, void* d_ws, size_t ws_size,
                              hipStream_t stream) {
    const int*   x      = (const int*)d_in[0];
    const float* emb    = (const float*)d_in[1];
    const float* W_w    = (const float*)d_in[2];
    const float* W_b    = (const float*)d_in[3];
    const float* head_w = (const float*)d_in[4];
    const float* head_b = (const float*)d_in[5];
    float* out = (float*)d_out;

    unsigned short* Wbf = (unsigned short*)d_ws;                          // 512 KB
    float*          hbuf = (float*)((char*)d_ws + 512 * 1024);            // 64 KB
    unsigned short* hhi  = (unsigned short*)((char*)d_ws + 576 * 1024);   // 32 KB
    unsigned short* hlo  = (unsigned short*)((char*)d_ws + 608 * 1024);   // 32 KB

    k_cvtw  <<<dim3(128),     dim3(256), 0, stream>>>(W_w, Wbf, hbuf);
    k_hidden<<<dim3(1024),    dim3(256), 0, stream>>>(x, emb, Wbf, W_b, hbuf);
    k_hsplit<<<dim3(64),      dim3(256), 0, stream>>>(hbuf, hhi, hlo);
    k_head  <<<dim3(V_ / 64), dim3(256), 0, stream>>>(hhi, hlo, head_w, head_b, out);
}

// Round 4
// 148.996 us; speedup vs baseline: 1.4428x; 1.1360x over previous
//
#include <hip/hip_runtime.h>
#include <math.h>
#include <stdint.h>

#define B_  32
#define T_  4096
#define D_  512
#define V_  32000
#define KW  128   // 0.9^128 = 1.4e-6 -> truncation error ~2e-5 at output, << 6.7e-3

typedef __attribute__((ext_vector_type(8))) short bf16x8_t;   // MFMA A/B frag (4 VGPRs)
typedef __attribute__((ext_vector_type(4))) float f32x4_t;    // MFMA C/D frag

// fp32 -> bf16 round-to-nearest-even
__device__ inline unsigned short f2bf(float f) {
    union { float f; uint32_t u; } c; c.f = f;
    return (unsigned short)((c.u + 0x7FFFu + ((c.u >> 16) & 1u)) >> 16);
}

__device__ inline uint4 cvt8(const float4 a, const float4 b) {
    union { unsigned short s[8]; uint4 v; } o;
    o.s[0] = f2bf(a.x); o.s[1] = f2bf(a.y); o.s[2] = f2bf(a.z); o.s[3] = f2bf(a.w);
    o.s[4] = f2bf(b.x); o.s[5] = f2bf(b.y); o.s[6] = f2bf(b.z); o.s[7] = f2bf(b.w);
    return o.v;
}

// -----------------------------------------------------------------------------
// k_prep: (blocks 0..127)   Ww fp32 -> Wbf bf16 [512][512], zero hbuf
//         (blocks 128..1151) gather last-128 window rows: Abf[4096][512] bf16,
//                            Abf[b*128 + t] = bf16(emb[x[b, T-128+t]])
// All conversions leave the GEMM K-loops entirely.
// -----------------------------------------------------------------------------
__global__ __launch_bounds__(256) void k_prep(const int* __restrict__ x,
                                              const float* __restrict__ emb,
                                              const float* __restrict__ Ww,
                                              unsigned short* __restrict__ Wbf,
                                              unsigned short* __restrict__ Abf,
                                              float* __restrict__ hbuf) {
    const int tid = threadIdx.x;
    if (blockIdx.x < 128) {
        const int gid = blockIdx.x * 256 + tid;      // 0..32767
        const int idx = gid * 8;
        const float4 a = *(const float4*)&Ww[idx];
        const float4 b = *(const float4*)&Ww[idx + 4];
        *(uint4*)&Wbf[idx] = cvt8(a, b);
        if (gid < B_ * D_) hbuf[gid] = 0.f;
    } else {
        const int j = (blockIdx.x - 128) * 256 + tid;  // 0..262143 octet-chunks
        const int r = j >> 6;                           // window row 0..4095
        const int c = (j & 63) * 8;                     // k offset
        const int b = r >> 7;
        const int row = x[b * T_ + (T_ - KW) + (r & 127)];
        const float* src = emb + (size_t)row * D_ + c;
        const float4 a = *(const float4*)src;
        const float4 bb = *(const float4*)(src + 4);
        *(uint4*)&Abf[(size_t)r * D_ + c] = cvt8(a, bb);
    }
}

// -----------------------------------------------------------------------------
// k_hidden: partial h[b][e] over a 32-row window slice, bf16 MFMA.
// Grid 1024 = b(32) x e-chunk(8, 64 wide) x t-slice(4, 32 rows) -> 4 blocks/CU.
// K-chunk 128 (4 phases only -> 4 barrier drains instead of 16). All staging
// via global_load_lds(16B) from pre-converted Abf/Wbf: zero VALU in the loop.
// LDS cells XOR-swizzled (cell = row*16 + (ko ^ (row&15))) so the frag
// ds_read_b128 pattern is 2-way-conflict-free (free on gfx950).
// Epilogue: tanh + geometric weight + reduce + fp32 atomicAdd into hbuf.
// -----------------------------------------------------------------------------
__global__ __launch_bounds__(256) void k_hidden(const unsigned short* __restrict__ Abf,
                                                const unsigned short* __restrict__ Wbf,
                                                const float* __restrict__ Wb,
                                                float* __restrict__ h) {
    __shared__ __align__(16) unsigned short As[512 * 8];   // 512 cells x 16B = 8 KB
    __shared__ __align__(16) unsigned short Bs[1024 * 8];  // 1024 cells = 16 KB
    __shared__ float red[8][64];                           // 2 KB

    const int tid = threadIdx.x;
    const int b   = blockIdx.x >> 5;
    const int e0  = ((blockIdx.x >> 2) & 7) * 64;
    const int ts  = blockIdx.x & 3;

    const int lane = tid & 63;
    const int w    = tid >> 6;
    const int m15  = lane & 15;
    const int q    = lane >> 4;
    const int mt   = w & 1;    // M-tile (16 of 32 rows)
    const int nh   = w >> 1;   // N-half (32 of 64 cols)

    f32x4_t acc[2];
    acc[0] = (f32x4_t){0.f, 0.f, 0.f, 0.f};
    acc[1] = (f32x4_t){0.f, 0.f, 0.f, 0.f};

    const size_t abase = (size_t)(b * KW + ts * 32) * D_;

    for (int k0 = 0; k0 < D_; k0 += 128) {
        __syncthreads();  // prior phase's frag reads complete before overwrite
        // stage A: 32 rows x 128 k bf16 = 512 cells, 2 per thread
#pragma unroll
        for (int i = 0; i < 2; i++) {
            const int j  = tid + 256 * i;           // cell index
            const int m  = j >> 4;
            const int ko = (j & 15) ^ (m & 15);     // XOR de-swizzle source
            const unsigned short* src = Abf + abase + (size_t)m * D_ + k0 + ko * 8;
            __builtin_amdgcn_global_load_lds(
                (const __attribute__((address_space(1))) void*)src,
                (__attribute__((address_space(3))) void*)&As[j * 8], 16, 0, 0);
        }
        // stage B: 64 rows x 128 k = 1024 cells, 4 per thread
#pragma unroll
        for (int i = 0; i < 4; i++) {
            const int j  = tid + 256 * i;
            const int n  = j >> 4;
            const int ko = (j & 15) ^ (n & 15);
            const unsigned short* src = Wbf + (size_t)(e0 + n) * D_ + k0 + ko * 8;
            __builtin_amdgcn_global_load_lds(
                (const __attribute__((address_space(1))) void*)src,
                (__attribute__((address_space(3))) void*)&Bs[j * 8], 16, 0, 0);
        }
        __syncthreads();

#pragma unroll
        for (int kk = 0; kk < 4; kk++) {
            const int ko = kk * 4 + q;
            const int mA = mt * 16 + m15;
            const int n0 = nh * 32 + m15;
            const int n1 = n0 + 16;
            const bf16x8_t af  = *(const bf16x8_t*)&As[(mA * 16 + (ko ^ m15)) * 8];
            const bf16x8_t bf0 = *(const bf16x8_t*)&Bs[(n0 * 16 + (ko ^ m15)) * 8];
            const bf16x8_t bf1 = *(const bf16x8_t*)&Bs[(n1 * 16 + (ko ^ m15)) * 8];
            acc[0] = __builtin_amdgcn_mfma_f32_16x16x32_bf16(af, bf0, acc[0], 0, 0, 0);
            acc[1] = __builtin_amdgcn_mfma_f32_16x16x32_bf16(af, bf1, acc[1], 0, 0, 0);
        }
    }

    // epilogue: tanh + geometric weight; C/D: row(M)=q*4+r, col(N)=m15
    float p[2] = {0.f, 0.f};
#pragma unroll
    for (int ni = 0; ni < 2; ni++) {
        const float wbv = Wb[e0 + nh * 32 + ni * 16 + m15];
#pragma unroll
        for (int r = 0; r < 4; r++) {
            const int twin = ts * 32 + mt * 16 + q * 4 + r;
            const float pre = acc[ni][r] + wbv;
            const float e2  = __expf(2.f * pre);
            const float u   = (e2 - 1.f) / (e2 + 1.f);
            const float wt  = 0.1f * exp2f((float)(127 - twin) * -0.15200309344504995f);
            p[ni] += wt * u;
        }
    }
#pragma unroll
    for (int ni = 0; ni < 2; ni++)
        red[mt * 4 + q][nh * 32 + ni * 16 + m15] = p[ni];
    __syncthreads();
    if (tid < 64) {
        float s = 0.f;
#pragma unroll
        for (int g = 0; g < 8; g++) s += red[g][tid];
        atomicAdd(&h[b * D_ + e0 + tid], s);
    }
}

// -----------------------------------------------------------------------------
// k_head: out[32][32000] = h @ head_w^T + head_b, plain-bf16 MFMA.
// Grid 1000 x 256 thr -> ~4 blocks/CU (LDS 33 KB), 4000 waves ~ 4/SIMD.
// Block: 32 v-rows (2 v-tiles) x full M=32 batch, split-K x2 across waves.
// h fp32 staged once into LDS as bf16 (stride 520 -> 2-way-free frag reads).
// head_w streamed fp32 (each row read exactly once device-wide), converted
// to bf16 in-register, depth-1 rotated prefetch. 2 MFMAs/kstep.
// -----------------------------------------------------------------------------
__global__ __launch_bounds__(256) void k_head(const float* __restrict__ h,
                                              const float* __restrict__ Whead,
                                              const float* __restrict__ bhead,
                                              float* __restrict__ out) {
    __shared__ __align__(16) unsigned short Hs[32 * 520 + 16];  // ~33 KB

    const int tid = threadIdx.x;
    // stage h -> bf16 LDS
#pragma unroll
    for (int i = 0; i < 8; i++) {
        const int g = (tid + 256 * i) * 8;   // flat float index, 8 per thread-iter
        const int r = g >> 9;
        const int c = g & 511;
        const float4 a = *(const float4*)&h[g];
        const float4 b = *(const float4*)&h[g + 4];
        *(uint4*)&Hs[r * 520 + c] = cvt8(a, b);
    }
    __syncthreads();

    const int lane = tid & 63;
    const int w    = tid >> 6;
    const int vt   = w & 1;    // v-tile within block
    const int kh   = w >> 1;   // K-half (256)
    const int n    = lane & 15;
    const int q    = lane >> 4;
    const int v    = blockIdx.x * 32 + vt * 16 + n;

    const float* __restrict__ wp = Whead + (size_t)v * D_ + kh * 256 + q * 8;

    f32x4_t acc0 = (f32x4_t){0.f, 0.f, 0.f, 0.f};
    f32x4_t acc1 = (f32x4_t){0.f, 0.f, 0.f, 0.f};

    float4 c0 = *(const float4*)&wp[0];
    float4 c1 = *(const float4*)&wp[4];
#pragma unroll
    for (int ks = 0; ks < 8; ks++) {
        float4 n0 = c0, n1 = c1;
        if (ks < 7) {                         // rotated depth-1 prefetch
            n0 = *(const float4*)&wp[(ks + 1) * 32];
            n1 = *(const float4*)&wp[(ks + 1) * 32 + 4];
        }
        union { uint4 u; bf16x8_t v8; } bfv;
        bfv.u = cvt8(c0, c1);
        const int kb = kh * 256 + ks * 32 + q * 8;   // col offset in shorts
        const bf16x8_t a0 = *(const bf16x8_t*)&Hs[n * 520 + kb];
        const bf16x8_t a1 = *(const bf16x8_t*)&Hs[(n + 16) * 520 + kb];
        acc0 = __builtin_amdgcn_mfma_f32_16x16x32_bf16(a0, bfv.v8, acc0, 0, 0, 0);
        acc1 = __builtin_amdgcn_mfma_f32_16x16x32_bf16(a1, bfv.v8, acc1, 0, 0, 0);
        c0 = n0; c1 = n1;
    }

    // split-K reduction through LDS (reuse Hs), then store with bias.
    __syncthreads();   // all h-LDS reads done; safe to reuse as fp32 scratch
    float* Rs = (float*)Hs;
    if (kh == 1) {
        float* p = &Rs[(vt * 64 + lane) * 8];
#pragma unroll
        for (int r = 0; r < 4; r++) { p[r] = acc0[r]; p[4 + r] = acc1[r]; }
    }
    __syncthreads();
    if (kh == 0) {
        const float* p = &Rs[(vt * 64 + lane) * 8];
        const float bb = bhead[v];
#pragma unroll
        for (int r = 0; r < 4; r++) {
            out[(size_t)(q * 4 + r) * V_ + v]      = acc0[r] + p[r]     + bb;
            out[(size_t)(16 + q * 4 + r) * V_ + v] = acc1[r] + p[4 + r] + bb;
        }
    }
}

extern "C" void kernel_launch(void* const* d_in, const int* in_sizes, int n_in,
                              void* d_out, int out_size, void* d_ws, size_t ws_size,
                              hipStream_t stream) {
    const int*   x      = (const int*)d_in[0];
    const float* emb    = (const float*)d_in[1];
    const float* W_w    = (const float*)d_in[2];
    const float* W_b    = (const float*)d_in[3];
    const float* head_w = (const float*)d_in[4];
    const float* head_b = (const float*)d_in[5];
    float* out = (float*)d_out;

    unsigned short* Wbf  = (unsigned short*)d_ws;                         // 512 KB
    float*          hbuf = (float*)((char*)d_ws + 512 * 1024);            // 64 KB
    unsigned short* Abf  = (unsigned short*)((char*)d_ws + 576 * 1024);   // 4 MB

    k_prep  <<<dim3(1152), dim3(256), 0, stream>>>(x, emb, W_w, Wbf, Abf, hbuf);
    k_hidden<<<dim3(1024), dim3(256), 0, stream>>>(Abf, Wbf, W_b, hbuf);
    k_head  <<<dim3(1000), dim3(256), 0, stream>>>(hbuf, head_w, head_b, out);
}